// Round 1
// baseline (364.002 us; speedup 1.0000x reference)
//
#include <hip/hip_runtime.h>
#include <hip/hip_bf16.h>

// Supervised contrastive loss, B=8192, D=256, T=0.07, 100 classes.
// Pipeline:
//   prep:  z f32 -> bf16 (ws), zero per-row positive counters
//   passA: fused bf16-MFMA z@z^T; per-row sum_neg; store positive logits to ws
//   passB: per-row sum of log1p(sum_neg * exp(-d)) over stored positives
//   final: mean over valid rows -> d_out[0]

#define BN 8192
#define DD 256
#define INV_T (1.0f / 0.07f)

typedef __attribute__((ext_vector_type(8))) __bf16 bf16x8;
typedef __attribute__((ext_vector_type(4))) float f32x4;

static __device__ __forceinline__ unsigned short f2bf(float f) {
    unsigned int u = __builtin_bit_cast(unsigned int, f);
    u = (u + 0x7FFFu + ((u >> 16) & 1u)) >> 16;   // RNE, inputs are finite
    return (unsigned short)u;
}

// ---------------- kernel 1: convert z to bf16, zero counters ----------------
__global__ __launch_bounds__(256) void k_prep(const float* __restrict__ z,
                                              unsigned short* __restrict__ zbf,
                                              int* __restrict__ cnt) {
    const int gid = blockIdx.x * 256 + threadIdx.x;       // 262144 threads
    const float4* z4 = (const float4*)z;
    float4 v0 = z4[gid * 2 + 0];
    float4 v1 = z4[gid * 2 + 1];
    unsigned short r[8];
    r[0] = f2bf(v0.x); r[1] = f2bf(v0.y); r[2] = f2bf(v0.z); r[3] = f2bf(v0.w);
    r[4] = f2bf(v1.x); r[5] = f2bf(v1.y); r[6] = f2bf(v1.z); r[7] = f2bf(v1.w);
    ((uint4*)zbf)[gid] = *(const uint4*)r;
    if (gid < BN) cnt[gid] = 0;
}

// ---------------- kernel 2: fused GEMM pass -------------------------------
// 256 blocks x 512 threads. Block owns 32 rows (2 row-waves x 16).
// 8 waves arranged 2 (row) x 4 (col); per iteration a block covers 256 cols.
__global__ __launch_bounds__(512) void k_passA(const unsigned short* __restrict__ zbf,
                                               const int* __restrict__ labels,
                                               float* __restrict__ sn_out,
                                               int* __restrict__ cnt,
                                               float* __restrict__ pos_d,
                                               int slots) {
    __shared__ int lab_lds[BN];
    __shared__ float sn_lds[32];
    const int tid = threadIdx.x;

    for (int t = tid; t < BN / 4; t += 512)
        ((int4*)lab_lds)[t] = ((const int4*)labels)[t];
    if (tid < 32) sn_lds[tid] = 0.f;
    __syncthreads();

    const int w    = tid >> 6;
    const int lane = tid & 63;
    const int l15  = lane & 15;
    const int lk   = lane >> 4;          // 0..3 -> k-chunk
    const int wrow = w & 1;              // 2 row groups of 16
    const int wcol = w >> 1;             // 4 col groups of 64
    const int rowbase = blockIdx.x * 32;
    const int r0 = rowbase + wrow * 16;

    // A fragments for this wave's 16 rows, full K=256, held in registers.
    bf16x8 a[8];
    const unsigned short* arow = zbf + (size_t)(r0 + l15) * DD + lk * 8;
#pragma unroll
    for (int s = 0; s < 8; ++s) a[s] = *(const bf16x8*)(arow + s * 32);

    int rlab[4];
#pragma unroll
    for (int r = 0; r < 4; ++r) rlab[r] = lab_lds[r0 + lk * 4 + r];

    float snp[4] = {0.f, 0.f, 0.f, 0.f};

    for (int it = 0; it < BN / 256; ++it) {
        const int c0 = it * 256 + wcol * 64;
#pragma unroll
        for (int g = 0; g < 4; ++g) {
            const int jcol = c0 + g * 16 + l15;
            const unsigned short* brow = zbf + (size_t)jcol * DD + lk * 8;
            f32x4 acc = {0.f, 0.f, 0.f, 0.f};
#pragma unroll
            for (int s = 0; s < 8; ++s) {
                bf16x8 b = *(const bf16x8*)(brow + s * 32);
                acc = __builtin_amdgcn_mfma_f32_16x16x32_bf16(a[s], b, acc, 0, 0, 0);
            }
            // epilogue: C layout col = lane&15, row = (lane>>4)*4 + reg
            const int lj = lab_lds[jcol];
#pragma unroll
            for (int r = 0; r < 4; ++r) {
                const int i = r0 + lk * 4 + r;
                const float d = acc[r] * INV_T;
                const float e = __expf(d);
                if (rlab[r] != lj) {
                    snp[r] += e;                      // negative
                } else if (i != jcol) {               // positive (exclude self)
                    int slot = atomicAdd(&cnt[i], 1);
                    if (slot < slots) pos_d[(size_t)i * slots + slot] = d;
                }
            }
        }
    }

    // reduce sum_neg across the 16 lanes (l15) that share the same rows
#pragma unroll
    for (int m = 1; m < 16; m <<= 1) {
#pragma unroll
        for (int r = 0; r < 4; ++r) snp[r] += __shfl_xor(snp[r], m, 64);
    }
    if (l15 == 0) {
#pragma unroll
        for (int r = 0; r < 4; ++r)
            atomicAdd(&sn_lds[wrow * 16 + lk * 4 + r], snp[r]);
    }
    __syncthreads();
    if (tid < 32) sn_out[rowbase + tid] = sn_lds[tid];
}

// ---------------- kernel 3: finish positive pairs -------------------------
__global__ __launch_bounds__(256) void k_passB(const float* __restrict__ sn_arr,
                                               const int* __restrict__ cnt,
                                               const float* __restrict__ pos_d,
                                               float* __restrict__ row_loss,
                                               int slots) {
    const int w = threadIdx.x >> 6, lane = threadIdx.x & 63;
    const int row = blockIdx.x * 4 + w;
    const float sn = sn_arr[row];
    const int c = cnt[row];
    const int ce = min(c, slots);
    float s = 0.f;
    for (int t = lane; t < ce; t += 64) {
        const float d = pos_d[(size_t)row * slots + t];
        s += log1pf(sn * __expf(-d));
    }
#pragma unroll
    for (int m = 1; m < 64; m <<= 1) s += __shfl_xor(s, m, 64);
    if (lane == 0) row_loss[row] = (c > 0) ? s / (float)c : 0.f;
}

// ---------------- kernel 4: final scalar reduce ---------------------------
__global__ __launch_bounds__(256) void k_final(const float* __restrict__ row_loss,
                                               const int* __restrict__ cnt,
                                               float* __restrict__ out) {
    __shared__ float ls[256];
    __shared__ float vs[256];
    float l = 0.f, v = 0.f;
    for (int r = threadIdx.x; r < BN; r += 256) {
        if (cnt[r] > 0) { l += row_loss[r]; v += 1.f; }
    }
    ls[threadIdx.x] = l; vs[threadIdx.x] = v;
    __syncthreads();
    for (int st = 128; st > 0; st >>= 1) {
        if (threadIdx.x < st) {
            ls[threadIdx.x] += ls[threadIdx.x + st];
            vs[threadIdx.x] += vs[threadIdx.x + st];
        }
        __syncthreads();
    }
    if (threadIdx.x == 0) out[0] = (vs[0] > 0.f) ? ls[0] / fmaxf(vs[0], 1.f) : 0.f;
}

extern "C" void kernel_launch(void* const* d_in, const int* in_sizes, int n_in,
                              void* d_out, int out_size, void* d_ws, size_t ws_size,
                              hipStream_t stream) {
    const float* z      = (const float*)d_in[0];
    const int*   labels = (const int*)d_in[1];
    float* out = (float*)d_out;

    char* ws = (char*)d_ws;
    // layout: zbf (4MB) | cnt (32KB) | sn (32KB) | row_loss (32KB) | pos_d (rest)
    unsigned short* zbf = (unsigned short*)ws;
    size_t off = (size_t)BN * DD * sizeof(unsigned short);
    int*   cnt = (int*)(ws + off);       off += BN * sizeof(int);
    float* sn  = (float*)(ws + off);     off += BN * sizeof(float);
    float* rl  = (float*)(ws + off);     off += BN * sizeof(float);
    float* pos_d = (float*)(ws + off);

    // positive-slot capacity from remaining workspace (expected ~82/row, cap 256)
    size_t remain = (ws_size > off) ? (ws_size - off) : 0;
    int slots = (int)(remain / ((size_t)BN * sizeof(float)));
    if (slots > 256) slots = 256;

    k_prep <<<1024, 256, 0, stream>>>(z, zbf, cnt);
    k_passA<<<256, 512, 0, stream>>>(zbf, labels, sn, cnt, pos_d, slots);
    k_passB<<<2048, 256, 0, stream>>>(sn, cnt, pos_d, rl, slots);
    k_final<<<1, 256, 0, stream>>>(rl, cnt, out);
}

// Round 2
// 343.062 us; speedup vs baseline: 1.0610x; 1.0610x over previous
//
#include <hip/hip_runtime.h>
#include <hip/hip_bf16.h>

// Supervised contrastive loss, B=8192, D=256, T=0.07, 100 classes.
// Pipeline:
//   prep:  z f32 -> bf16 (ws), zero counters + sum_neg accumulators
//   passA: fused bf16-MFMA z@z^T; per-row sum_neg (global atomic across col
//          chunks); store positive logits to ws. Grid 256 row-blocks x 4 col
//          chunks for 32 waves/CU occupancy (R0 was 8 waves/CU, latency-bound).
//   passB: per-row sum of log1p(sum_neg * exp(-d)) over stored positives
//   final: mean over valid rows -> d_out[0]

#define BN 8192
#define DD 256
#define INV_T (1.0f / 0.07f)
#define COLCHUNK 2048

typedef __attribute__((ext_vector_type(8))) __bf16 bf16x8;
typedef __attribute__((ext_vector_type(4))) float f32x4;

static __device__ __forceinline__ unsigned short f2bf(float f) {
    unsigned int u = __builtin_bit_cast(unsigned int, f);
    u = (u + 0x7FFFu + ((u >> 16) & 1u)) >> 16;   // RNE, inputs are finite
    return (unsigned short)u;
}

// ---------------- kernel 1: convert z to bf16, zero counters ----------------
__global__ __launch_bounds__(256) void k_prep(const float* __restrict__ z,
                                              unsigned short* __restrict__ zbf,
                                              int* __restrict__ cnt,
                                              float* __restrict__ sn) {
    const int gid = blockIdx.x * 256 + threadIdx.x;       // 262144 threads
    const float4* z4 = (const float4*)z;
    float4 v0 = z4[gid * 2 + 0];
    float4 v1 = z4[gid * 2 + 1];
    unsigned short r[8];
    r[0] = f2bf(v0.x); r[1] = f2bf(v0.y); r[2] = f2bf(v0.z); r[3] = f2bf(v0.w);
    r[4] = f2bf(v1.x); r[5] = f2bf(v1.y); r[6] = f2bf(v1.z); r[7] = f2bf(v1.w);
    ((uint4*)zbf)[gid] = *(const uint4*)r;
    if (gid < BN) { cnt[gid] = 0; sn[gid] = 0.f; }
}

// ---------------- kernel 2: fused GEMM pass -------------------------------
// Grid (256, 4) x 512 threads. Block owns 32 rows (2 row-waves x 16) and a
// 2048-col chunk. 8 waves arranged 2 (row) x 4 (col); per iteration a block
// covers 256 cols.
__global__ __launch_bounds__(512) void k_passA(const unsigned short* __restrict__ zbf,
                                               const int* __restrict__ labels,
                                               float* __restrict__ sn_out,
                                               int* __restrict__ cnt,
                                               float* __restrict__ pos_d,
                                               int slots) {
    __shared__ int lab_lds[BN];
    __shared__ float sn_lds[32];
    const int tid = threadIdx.x;

    for (int t = tid; t < BN / 4; t += 512)
        ((int4*)lab_lds)[t] = ((const int4*)labels)[t];
    if (tid < 32) sn_lds[tid] = 0.f;
    __syncthreads();

    const int w    = tid >> 6;
    const int lane = tid & 63;
    const int l15  = lane & 15;
    const int lk   = lane >> 4;          // 0..3 -> k-chunk
    const int wrow = w & 1;              // 2 row groups of 16
    const int wcol = w >> 1;             // 4 col groups of 64
    const int rowbase = blockIdx.x * 32;
    const int r0 = rowbase + wrow * 16;
    const int colbase = blockIdx.y * COLCHUNK;

    // A fragments for this wave's 16 rows, full K=256, held in registers.
    bf16x8 a[8];
    const unsigned short* arow = zbf + (size_t)(r0 + l15) * DD + lk * 8;
#pragma unroll
    for (int s = 0; s < 8; ++s) a[s] = *(const bf16x8*)(arow + s * 32);

    int rlab[4];
#pragma unroll
    for (int r = 0; r < 4; ++r) rlab[r] = lab_lds[r0 + lk * 4 + r];

    float snp[4] = {0.f, 0.f, 0.f, 0.f};

    for (int it = 0; it < COLCHUNK / 256; ++it) {
        const int c0 = colbase + it * 256 + wcol * 64;
#pragma unroll
        for (int g = 0; g < 4; ++g) {
            const int jcol = c0 + g * 16 + l15;
            const unsigned short* brow = zbf + (size_t)jcol * DD + lk * 8;
            f32x4 acc = {0.f, 0.f, 0.f, 0.f};
#pragma unroll
            for (int s = 0; s < 8; ++s) {
                bf16x8 b = *(const bf16x8*)(brow + s * 32);
                acc = __builtin_amdgcn_mfma_f32_16x16x32_bf16(a[s], b, acc, 0, 0, 0);
            }
            // epilogue: C layout col = lane&15, row = (lane>>4)*4 + reg
            const int lj = lab_lds[jcol];
#pragma unroll
            for (int r = 0; r < 4; ++r) {
                const int i = r0 + lk * 4 + r;
                const float d = acc[r] * INV_T;
                const float e = __expf(d);
                if (rlab[r] != lj) {
                    snp[r] += e;                      // negative
                } else if (i != jcol) {               // positive (exclude self)
                    int slot = atomicAdd(&cnt[i], 1);
                    if (slot < slots) pos_d[(size_t)i * slots + slot] = d;
                }
            }
        }
    }

    // reduce sum_neg across the 16 lanes (l15) that share the same rows
#pragma unroll
    for (int m = 1; m < 16; m <<= 1) {
#pragma unroll
        for (int r = 0; r < 4; ++r) snp[r] += __shfl_xor(snp[r], m, 64);
    }
    if (l15 == 0) {
#pragma unroll
        for (int r = 0; r < 4; ++r)
            atomicAdd(&sn_lds[wrow * 16 + lk * 4 + r], snp[r]);
    }
    __syncthreads();
    if (tid < 32) atomicAdd(&sn_out[rowbase + tid], sn_lds[tid]);
}

// ---------------- kernel 3: finish positive pairs -------------------------
__global__ __launch_bounds__(256) void k_passB(const float* __restrict__ sn_arr,
                                               const int* __restrict__ cnt,
                                               const float* __restrict__ pos_d,
                                               float* __restrict__ row_loss,
                                               int slots) {
    const int w = threadIdx.x >> 6, lane = threadIdx.x & 63;
    const int row = blockIdx.x * 4 + w;
    const float sn = sn_arr[row];
    const int c = cnt[row];
    const int ce = min(c, slots);
    float s = 0.f;
    for (int t = lane; t < ce; t += 64) {
        const float d = pos_d[(size_t)row * slots + t];
        s += log1pf(sn * __expf(-d));
    }
#pragma unroll
    for (int m = 1; m < 64; m <<= 1) s += __shfl_xor(s, m, 64);
    if (lane == 0) row_loss[row] = (c > 0) ? s / (float)c : 0.f;
}

// ---------------- kernel 4: final scalar reduce ---------------------------
__global__ __launch_bounds__(256) void k_final(const float* __restrict__ row_loss,
                                               const int* __restrict__ cnt,
                                               float* __restrict__ out) {
    __shared__ float ls[256];
    __shared__ float vs[256];
    float l = 0.f, v = 0.f;
    for (int r = threadIdx.x; r < BN; r += 256) {
        if (cnt[r] > 0) { l += row_loss[r]; v += 1.f; }
    }
    ls[threadIdx.x] = l; vs[threadIdx.x] = v;
    __syncthreads();
    for (int st = 128; st > 0; st >>= 1) {
        if (threadIdx.x < st) {
            ls[threadIdx.x] += ls[threadIdx.x + st];
            vs[threadIdx.x] += vs[threadIdx.x + st];
        }
        __syncthreads();
    }
    if (threadIdx.x == 0) out[0] = (vs[0] > 0.f) ? ls[0] / fmaxf(vs[0], 1.f) : 0.f;
}

extern "C" void kernel_launch(void* const* d_in, const int* in_sizes, int n_in,
                              void* d_out, int out_size, void* d_ws, size_t ws_size,
                              hipStream_t stream) {
    const float* z      = (const float*)d_in[0];
    const int*   labels = (const int*)d_in[1];
    float* out = (float*)d_out;

    char* ws = (char*)d_ws;
    // layout: zbf (4MB) | cnt (32KB) | sn (32KB) | row_loss (32KB) | pos_d (rest)
    unsigned short* zbf = (unsigned short*)ws;
    size_t off = (size_t)BN * DD * sizeof(unsigned short);
    int*   cnt = (int*)(ws + off);       off += BN * sizeof(int);
    float* sn  = (float*)(ws + off);     off += BN * sizeof(float);
    float* rl  = (float*)(ws + off);     off += BN * sizeof(float);
    float* pos_d = (float*)(ws + off);

    // positive-slot capacity from remaining workspace (expected ~82/row, cap 256)
    size_t remain = (ws_size > off) ? (ws_size - off) : 0;
    int slots = (int)(remain / ((size_t)BN * sizeof(float)));
    if (slots > 256) slots = 256;

    k_prep <<<1024, 256, 0, stream>>>(z, zbf, cnt, sn);
    dim3 gridA(256, 4);
    k_passA<<<gridA, 512, 0, stream>>>(zbf, labels, sn, cnt, pos_d, slots);
    k_passB<<<2048, 256, 0, stream>>>(sn, cnt, pos_d, rl, slots);
    k_final<<<1, 256, 0, stream>>>(rl, cnt, out);
}

// Round 3
// 283.702 us; speedup vs baseline: 1.2830x; 1.2092x over previous
//
#include <hip/hip_runtime.h>
#include <hip/hip_bf16.h>

// Supervised contrastive loss, B=8192, D=256, T=0.07, 100 classes.
// Pipeline:
//   prep:  z f32 -> bf16 (ws), zero cnt + sum_neg
//   passA: tiled bf16-MFMA z@z^T (128x128 tile, LDS-staged via global_load_lds,
//          XOR-swizzled, double-buffered) with fused epilogue:
//          per-row sum_neg (global atomics) + positive-logit store.
//   passB: per-row sum of log1p(sum_neg * exp(-d)) over stored positives
//   final: mean over valid rows -> d_out[0]

#define BN 8192
#define DD 256
#define INV_T (1.0f / 0.07f)
#define BM 128
#define BKB 128   // bytes of K per staged chunk (64 bf16)

typedef __attribute__((ext_vector_type(8))) __bf16 bf16x8;
typedef __attribute__((ext_vector_type(4))) float f32x4;

typedef const __attribute__((address_space(1))) void gas_void;
typedef __attribute__((address_space(3))) void las_void;

static __device__ __forceinline__ void gld_lds16(const void* g, void* l) {
    __builtin_amdgcn_global_load_lds((gas_void*)g, (las_void*)l, 16, 0, 0);
}

static __device__ __forceinline__ unsigned short f2bf(float f) {
    unsigned int u = __builtin_bit_cast(unsigned int, f);
    u = (u + 0x7FFFu + ((u >> 16) & 1u)) >> 16;   // RNE, inputs are finite
    return (unsigned short)u;
}

// ---------------- kernel 1: convert z to bf16, zero cnt/sn ----------------
__global__ __launch_bounds__(256) void k_prep(const float* __restrict__ z,
                                              unsigned short* __restrict__ zbf,
                                              int* __restrict__ cnt,
                                              float* __restrict__ sn) {
    const int gid = blockIdx.x * 256 + threadIdx.x;       // 262144 threads
    const float4* z4 = (const float4*)z;
    float4 v0 = z4[gid * 2 + 0];
    float4 v1 = z4[gid * 2 + 1];
    unsigned short r[8];
    r[0] = f2bf(v0.x); r[1] = f2bf(v0.y); r[2] = f2bf(v0.z); r[3] = f2bf(v0.w);
    r[4] = f2bf(v1.x); r[5] = f2bf(v1.y); r[6] = f2bf(v1.z); r[7] = f2bf(v1.w);
    ((uint4*)zbf)[gid] = *(const uint4*)r;
    if (gid < BN) { cnt[gid] = 0; sn[gid] = 0.f; }
}

// ---------------- kernel 2: tiled GEMM + fused epilogue -------------------
// Grid 64x64 = 4096 blocks, 256 threads (4 waves, 2x2 of 64x64 each).
__global__ __launch_bounds__(256) void k_passA(const unsigned short* __restrict__ zbf,
                                               const int* __restrict__ labels,
                                               float* __restrict__ sn_out,
                                               int* __restrict__ cnt,
                                               float* __restrict__ pos_d,
                                               int slots) {
    __shared__ unsigned short Ab[2][BM * 64];   // [row][64 bf16], XOR-swizzled, 16KB each
    __shared__ unsigned short Bb[2][BM * 64];
    __shared__ int rlab_lds[BM], clab_lds[BM];

    const int tid = threadIdx.x;
    const int bx = blockIdx.x & 63;   // col tile
    const int by = blockIdx.x >> 6;   // row tile
    const int rowbase = by * BM, colbase = bx * BM;

    if (tid < 32) ((int4*)rlab_lds)[tid] = ((const int4*)(labels + rowbase))[tid];
    else if (tid < 64) ((int4*)clab_lds)[tid - 32] = ((const int4*)(labels + colbase))[tid - 32];

    const char* zb = (const char*)zbf;
    auto stage = [&](int buf, int kk) {
        const char* gA = zb + (size_t)rowbase * 512 + kk * BKB;
        const char* gB = zb + (size_t)colbase * 512 + kk * BKB;
#pragma unroll
        for (int q = 0; q < 4; ++q) {
            const int s = (q * 256 + tid) * 16;           // linear LDS byte offset
            const int row = s >> 7;
            const int koff = s & 127;
            const int ksrc = koff ^ ((row & 7) << 4);     // pre-swizzled source
            gld_lds16(gA + (size_t)row * 512 + ksrc, (char*)Ab[buf] + s);
            gld_lds16(gB + (size_t)row * 512 + ksrc, (char*)Bb[buf] + s);
        }
    };

    stage(0, 0);

    const int w = tid >> 6, lane = tid & 63;
    const int l15 = lane & 15, lk = lane >> 4;
    const int wrow = w >> 1, wcol = w & 1;

    f32x4 acc[4][4] = {};

    __syncthreads();                                      // drains vmcnt for stage(0)

    for (int kk = 0; kk < 4; ++kk) {
        if (kk < 3) stage((kk + 1) & 1, kk + 1);
        const char* Ac = (const char*)Ab[kk & 1];
        const char* Bc = (const char*)Bb[kk & 1];
#pragma unroll
        for (int ks = 0; ks < 2; ++ks) {
            bf16x8 a[4], b[4];
#pragma unroll
            for (int m = 0; m < 4; ++m) {
                const int row = wrow * 64 + m * 16 + l15;
                const int koff = (ks * 64 + lk * 16) ^ ((row & 7) << 4);
                a[m] = *(const bf16x8*)(Ac + row * 128 + koff);
            }
#pragma unroll
            for (int n = 0; n < 4; ++n) {
                const int col = wcol * 64 + n * 16 + l15;
                const int koff = (ks * 64 + lk * 16) ^ ((col & 7) << 4);
                b[n] = *(const bf16x8*)(Bc + col * 128 + koff);
            }
#pragma unroll
            for (int m = 0; m < 4; ++m)
#pragma unroll
                for (int n = 0; n < 4; ++n)
                    acc[m][n] = __builtin_amdgcn_mfma_f32_16x16x32_bf16(a[m], b[n], acc[m][n], 0, 0, 0);
        }
        __syncthreads();
    }

    // ---- fused epilogue ----
    int rl[4][4];
#pragma unroll
    for (int m = 0; m < 4; ++m)
#pragma unroll
        for (int r = 0; r < 4; ++r)
            rl[m][r] = rlab_lds[wrow * 64 + m * 16 + lk * 4 + r];
    int cl[4];
#pragma unroll
    for (int n = 0; n < 4; ++n) cl[n] = clab_lds[wcol * 64 + n * 16 + l15];

    float snp[4][4] = {};
#pragma unroll
    for (int m = 0; m < 4; ++m) {
#pragma unroll
        for (int n = 0; n < 4; ++n) {
#pragma unroll
            for (int r = 0; r < 4; ++r) {
                const float d = acc[m][n][r] * INV_T;
                const float e = __expf(d);
                if (rl[m][r] != cl[n]) {
                    snp[m][r] += e;                       // negative
                } else {
                    const int i = rowbase + wrow * 64 + m * 16 + lk * 4 + r;
                    const int j = colbase + wcol * 64 + n * 16 + l15;
                    if (i != j) {                         // positive (exclude self)
                        int slot = atomicAdd(&cnt[i], 1);
                        if (slot < slots) pos_d[(size_t)i * slots + slot] = d;
                    }
                }
            }
        }
    }
    // reduce sum_neg across the 16 lanes sharing each row, then global atomic
#pragma unroll
    for (int m = 0; m < 4; ++m) {
#pragma unroll
        for (int r = 0; r < 4; ++r) {
            float v = snp[m][r];
            v += __shfl_xor(v, 1, 64);
            v += __shfl_xor(v, 2, 64);
            v += __shfl_xor(v, 4, 64);
            v += __shfl_xor(v, 8, 64);
            if (l15 == 0)
                atomicAdd(&sn_out[rowbase + wrow * 64 + m * 16 + lk * 4 + r], v);
        }
    }
}

// ---------------- kernel 3: finish positive pairs -------------------------
__global__ __launch_bounds__(256) void k_passB(const float* __restrict__ sn_arr,
                                               const int* __restrict__ cnt,
                                               const float* __restrict__ pos_d,
                                               float* __restrict__ row_loss,
                                               int slots) {
    const int w = threadIdx.x >> 6, lane = threadIdx.x & 63;
    const int row = blockIdx.x * 4 + w;
    const float sn = sn_arr[row];
    const int c = cnt[row];
    const int ce = min(c, slots);
    float s = 0.f;
    for (int t = lane; t < ce; t += 64) {
        const float d = pos_d[(size_t)row * slots + t];
        s += log1pf(sn * __expf(-d));
    }
#pragma unroll
    for (int m = 1; m < 64; m <<= 1) s += __shfl_xor(s, m, 64);
    if (lane == 0) row_loss[row] = (c > 0) ? s / (float)c : 0.f;
}

// ---------------- kernel 4: final scalar reduce ---------------------------
__global__ __launch_bounds__(256) void k_final(const float* __restrict__ row_loss,
                                               const int* __restrict__ cnt,
                                               float* __restrict__ out) {
    __shared__ float ls[256];
    __shared__ float vs[256];
    float l = 0.f, v = 0.f;
    for (int r = threadIdx.x; r < BN; r += 256) {
        if (cnt[r] > 0) { l += row_loss[r]; v += 1.f; }
    }
    ls[threadIdx.x] = l; vs[threadIdx.x] = v;
    __syncthreads();
    for (int st = 128; st > 0; st >>= 1) {
        if (threadIdx.x < st) {
            ls[threadIdx.x] += ls[threadIdx.x + st];
            vs[threadIdx.x] += vs[threadIdx.x + st];
        }
        __syncthreads();
    }
    if (threadIdx.x == 0) out[0] = (vs[0] > 0.f) ? ls[0] / fmaxf(vs[0], 1.f) : 0.f;
}

extern "C" void kernel_launch(void* const* d_in, const int* in_sizes, int n_in,
                              void* d_out, int out_size, void* d_ws, size_t ws_size,
                              hipStream_t stream) {
    const float* z      = (const float*)d_in[0];
    const int*   labels = (const int*)d_in[1];
    float* out = (float*)d_out;

    char* ws = (char*)d_ws;
    // layout: zbf (4MB) | cnt (32KB) | sn (32KB) | row_loss (32KB) | pos_d (rest)
    unsigned short* zbf = (unsigned short*)ws;
    size_t off = (size_t)BN * DD * sizeof(unsigned short);
    int*   cnt = (int*)(ws + off);       off += BN * sizeof(int);
    float* sn  = (float*)(ws + off);     off += BN * sizeof(float);
    float* rl  = (float*)(ws + off);     off += BN * sizeof(float);
    float* pos_d = (float*)(ws + off);

    size_t remain = (ws_size > off) ? (ws_size - off) : 0;
    int slots = (int)(remain / ((size_t)BN * sizeof(float)));
    if (slots > 256) slots = 256;

    k_prep <<<1024, 256, 0, stream>>>(z, zbf, cnt, sn);
    k_passA<<<4096, 256, 0, stream>>>(zbf, labels, sn, cnt, pos_d, slots);
    k_passB<<<2048, 256, 0, stream>>>(sn, cnt, pos_d, rl, slots);
    k_final<<<1, 256, 0, stream>>>(rl, cnt, out);
}

// Round 4
// 98.567 us; speedup vs baseline: 3.6930x; 2.8783x over previous
//
#include <hip/hip_runtime.h>
#include <hip/hip_bf16.h>

// Supervised contrastive loss, B=8192, D=256, T=0.07, 100 classes.
//   prep:   z f32 -> bf16 (ws); zero cls_cnt
//   bucket: per-class index lists (atomic append, order-independent sum later)
//   passA:  pure row sums of exp(z@z^T/T), diagonal masked. No labels, no
//           atomics: 256 blocks = 64 row-tiles x 4 col-quarters, partial sums
//           written to sn_part[quarter][row]. m97-style: A frags in regs,
//           B (128 cols x K=256) double-buffered in XOR-swizzled LDS via
//           global_load_lds w16.
//   passB:  per class: gather members to LDS, all-pairs MFMA (bitwise-equal d
//           to passA) -> sum_same -> sum_neg = sum_all - sum_same; second MFMA
//           pass computes sum_j log1p(sum_neg_i * exp(-d_ij)) -> row_loss.
//   final:  mean over valid rows -> d_out[0]

#define BN 8192
#define DD 256
#define INV_T (1.0f / 0.07f)
#define CAPI 256     // cls_idx capacity per class
#define CAP 160      // max class rows processed (mean 82, sigma 9)

typedef __attribute__((ext_vector_type(8))) __bf16 bf16x8;
typedef __attribute__((ext_vector_type(4))) float f32x4;

typedef const __attribute__((address_space(1))) void gas_void;
typedef __attribute__((address_space(3))) void las_void;

static __device__ __forceinline__ void gld_lds16(const void* g, void* l) {
    __builtin_amdgcn_global_load_lds((gas_void*)g, (las_void*)l, 16, 0, 0);
}

static __device__ __forceinline__ unsigned short f2bf(float f) {
    unsigned int u = __builtin_bit_cast(unsigned int, f);
    u = (u + 0x7FFFu + ((u >> 16) & 1u)) >> 16;   // RNE, inputs finite
    return (unsigned short)u;
}

// ---------------- kernel 1: convert z to bf16, zero cls_cnt ---------------
__global__ __launch_bounds__(256) void k_prep(const float* __restrict__ z,
                                              unsigned short* __restrict__ zbf,
                                              int* __restrict__ cls_cnt) {
    const int gid = blockIdx.x * 256 + threadIdx.x;       // 262144 threads
    const float4* z4 = (const float4*)z;
    float4 v0 = z4[gid * 2 + 0];
    float4 v1 = z4[gid * 2 + 1];
    unsigned short r[8];
    r[0] = f2bf(v0.x); r[1] = f2bf(v0.y); r[2] = f2bf(v0.z); r[3] = f2bf(v0.w);
    r[4] = f2bf(v1.x); r[5] = f2bf(v1.y); r[6] = f2bf(v1.z); r[7] = f2bf(v1.w);
    ((uint4*)zbf)[gid] = *(const uint4*)r;
    if (blockIdx.x == 0 && threadIdx.x < 100) cls_cnt[threadIdx.x] = 0;
}

// ---------------- kernel 1b: bucket rows by class -------------------------
__global__ __launch_bounds__(256) void k_bucket(const int* __restrict__ labels,
                                                int* __restrict__ cls_cnt,
                                                int* __restrict__ cls_idx) {
    const int gid = blockIdx.x * 256 + threadIdx.x;
    if (gid < BN) {
        const int c = labels[gid];
        const int slot = atomicAdd(&cls_cnt[c], 1);
        if (slot < CAPI) cls_idx[c * CAPI + slot] = gid;
    }
}

// ---------------- kernel 2: row sums of exp(z z^T / T), diag masked -------
// Grid 256 = 64 row-tiles x 4 col-quarters. 512 thr = 8 waves (4 wr x 2 wc).
// Block: 128 rows x 2048 cols; per N-step 128 cols staged in LDS (dbuf).
__global__ __launch_bounds__(512) void k_passA(const unsigned short* __restrict__ zbf,
                                               float* __restrict__ sn_part) {
    __shared__ char Bb[2 * 65536];            // [2][128 cols][512 B], swizzled
    __shared__ float sn_lds[128];

    const int tid = threadIdx.x;
    const int by = blockIdx.x >> 2;
    const int cq = blockIdx.x & 3;
    const int rowbase = by * 128;
    const int colbase = cq * 2048;
    const char* zb = (const char*)zbf;

    auto stage = [&](int buf, int ns) {
        const char* gB = zb + ((size_t)(colbase + ns * 128)) * 512;
        char* lbase = Bb + buf * 65536;
#pragma unroll
        for (int q = 0; q < 8; ++q) {
            const int s = (q * 512 + tid) * 16;          // linear LDS offset
            const int col = s >> 9;
            const int koff = s & 511;
            const int ksrc = koff ^ ((col & 7) << 4);    // pre-swizzled source
            gld_lds16(gB + (size_t)col * 512 + ksrc, lbase + s);
        }
    };

    stage(0, 0);

    const int w = tid >> 6, lane = tid & 63;
    const int l15 = lane & 15, lk = lane >> 4;
    const int wr = w >> 1, wc = w & 1;

    // A fragments: this wave's 32 rows, full K=256, in registers (64 VGPR).
    bf16x8 a[2][8];
#pragma unroll
    for (int m = 0; m < 2; ++m) {
        const char* ap = zb + (size_t)(rowbase + wr * 32 + m * 16 + l15) * 512 + lk * 16;
#pragma unroll
        for (int kf = 0; kf < 8; ++kf) a[m][kf] = *(const bf16x8*)(ap + kf * 64);
    }
    int iglob[2][4];
#pragma unroll
    for (int m = 0; m < 2; ++m)
#pragma unroll
        for (int rr = 0; rr < 4; ++rr)
            iglob[m][rr] = rowbase + wr * 32 + m * 16 + lk * 4 + rr;

    if (tid < 128) sn_lds[tid] = 0.f;
    float snp[2][4] = {};

    __syncthreads();                                     // stage(0) drained

    for (int ns = 0; ns < 16; ++ns) {
        const int buf = ns & 1;
        if (ns < 15) stage(buf ^ 1, ns + 1);
        const char* bp0 = Bb + buf * 65536;
#pragma unroll
        for (int n = 0; n < 4; ++n) {
            const int colL = wc * 64 + n * 16 + l15;
            const int sw = (colL & 7) << 4;
            const char* bp = bp0 + colL * 512;
            bf16x8 b[8];
#pragma unroll
            for (int kf = 0; kf < 8; ++kf)
                b[kf] = *(const bf16x8*)(bp + ((lk * 16 + kf * 64) ^ sw));
            const int jj = colbase + ns * 128 + colL;
#pragma unroll
            for (int m = 0; m < 2; ++m) {
                f32x4 acc = {};
#pragma unroll
                for (int kf = 0; kf < 8; ++kf)
                    acc = __builtin_amdgcn_mfma_f32_16x16x32_bf16(a[m][kf], b[kf], acc, 0, 0, 0);
#pragma unroll
                for (int rr = 0; rr < 4; ++rr) {
                    float e = __expf(acc[rr] * INV_T);
                    if (iglob[m][rr] == jj) e = 0.f;     // mask diagonal
                    snp[m][rr] += e;
                }
            }
        }
        __syncthreads();
    }

    // reduce across the 16 l15 lanes sharing each row, accumulate in LDS
#pragma unroll
    for (int m = 0; m < 2; ++m) {
#pragma unroll
        for (int rr = 0; rr < 4; ++rr) {
            float v = snp[m][rr];
            v += __shfl_xor(v, 1, 64);
            v += __shfl_xor(v, 2, 64);
            v += __shfl_xor(v, 4, 64);
            v += __shfl_xor(v, 8, 64);
            if (l15 == 0)
                atomicAdd(&sn_lds[wr * 32 + m * 16 + lk * 4 + rr], v);
        }
    }
    __syncthreads();
    if (tid < 128)
        sn_part[(size_t)cq * BN + rowbase + tid] = sn_lds[tid];
}

// ---------------- kernel 3: per-class positive pairs ----------------------
// 100 blocks x 256 thr. Gather class rows to swizzled LDS; all-pairs MFMA.
__global__ __launch_bounds__(256) void k_passB(const unsigned short* __restrict__ zbf,
                                               const float* __restrict__ sn_part,
                                               const int* __restrict__ cls_cnt,
                                               const int* __restrict__ cls_idx,
                                               float* __restrict__ row_loss,
                                               float* __restrict__ validf) {
    __shared__ char Zc[CAP * 512];            // swizzled [row][512 B]
    __shared__ int glist[CAP];
    __shared__ float snl[CAP];
    __shared__ float sums[CAP];

    const int c = blockIdx.x;
    const int tid = threadIdx.x;
    const int w = tid >> 6, lane = tid & 63;
    const int l15 = lane & 15, lk = lane >> 4;
    const char* zb = (const char*)zbf;

    const int n_c = min(cls_cnt[c], CAP);
    const int nt = (n_c + 15) >> 4;
    const int rows_p = nt * 16;

    if (tid < n_c) glist[tid] = cls_idx[c * CAPI + tid];
    __syncthreads();

    // gather member embeddings (zero-pad tail rows), swizzled LDS writes
    for (int e = w; e < rows_p; e += 4) {
        uint2 v = {0u, 0u};
        if (e < n_c) v = *(const uint2*)(zb + (size_t)glist[e] * 512 + lane * 8);
        *(uint2*)(Zc + e * 512 + ((lane * 8) ^ ((e & 7) << 4))) = v;
    }
    if (tid < n_c) {
        const int gi = glist[tid];
        snl[tid] = sn_part[gi] + sn_part[BN + gi] + sn_part[2 * BN + gi] + sn_part[3 * BN + gi];
    }
    __syncthreads();

    // ---- pass 1: sum_same (exp of same-class logits, self excluded) ----
    for (int mi = w; mi < nt; mi += 4) {
        const int rowA = mi * 16 + l15;
        bf16x8 a[8];
        const char* ap = Zc + rowA * 512;
        const int swa = (rowA & 7) << 4;
#pragma unroll
        for (int kf = 0; kf < 8; ++kf)
            a[kf] = *(const bf16x8*)(ap + ((lk * 16 + kf * 64) ^ swa));
        float sp[4] = {};
        for (int nj = 0; nj < nt; ++nj) {
            const int colB = nj * 16 + l15;
            bf16x8 b[8];
            const char* bp = Zc + colB * 512;
            const int swb = (colB & 7) << 4;
#pragma unroll
            for (int kf = 0; kf < 8; ++kf)
                b[kf] = *(const bf16x8*)(bp + ((lk * 16 + kf * 64) ^ swb));
            f32x4 acc = {};
#pragma unroll
            for (int kf = 0; kf < 8; ++kf)
                acc = __builtin_amdgcn_mfma_f32_16x16x32_bf16(a[kf], b[kf], acc, 0, 0, 0);
            const int j = colB;                 // local col index
#pragma unroll
            for (int rr = 0; rr < 4; ++rr) {
                const int i = mi * 16 + lk * 4 + rr;
                float e = __expf(acc[rr] * INV_T);
                sp[rr] += (j < n_c && i != j) ? e : 0.f;
            }
        }
#pragma unroll
        for (int rr = 0; rr < 4; ++rr) {
            float v = sp[rr];
            v += __shfl_xor(v, 1, 64);
            v += __shfl_xor(v, 2, 64);
            v += __shfl_xor(v, 4, 64);
            v += __shfl_xor(v, 8, 64);
            if (l15 == 0) sums[mi * 16 + lk * 4 + rr] = v;
        }
    }
    __syncthreads();
    if (tid < n_c) snl[tid] = snl[tid] - sums[tid];   // now sum_neg
    __syncthreads();

    // ---- pass 2: pair losses ----
    for (int mi = w; mi < nt; mi += 4) {
        const int rowA = mi * 16 + l15;
        bf16x8 a[8];
        const char* ap = Zc + rowA * 512;
        const int swa = (rowA & 7) << 4;
#pragma unroll
        for (int kf = 0; kf < 8; ++kf)
            a[kf] = *(const bf16x8*)(ap + ((lk * 16 + kf * 64) ^ swa));
        float sneg[4];
#pragma unroll
        for (int rr = 0; rr < 4; ++rr) {
            const int i = mi * 16 + lk * 4 + rr;
            sneg[rr] = (i < n_c) ? snl[i] : 0.f;
        }
        float sp[4] = {};
        for (int nj = 0; nj < nt; ++nj) {
            const int colB = nj * 16 + l15;
            bf16x8 b[8];
            const char* bp = Zc + colB * 512;
            const int swb = (colB & 7) << 4;
#pragma unroll
            for (int kf = 0; kf < 8; ++kf)
                b[kf] = *(const bf16x8*)(bp + ((lk * 16 + kf * 64) ^ swb));
            f32x4 acc = {};
#pragma unroll
            for (int kf = 0; kf < 8; ++kf)
                acc = __builtin_amdgcn_mfma_f32_16x16x32_bf16(a[kf], b[kf], acc, 0, 0, 0);
            const int j = colB;
#pragma unroll
            for (int rr = 0; rr < 4; ++rr) {
                const int i = mi * 16 + lk * 4 + rr;
                const float t = log1pf(sneg[rr] * __expf(-acc[rr] * INV_T));
                sp[rr] += (j < n_c && i != j) ? t : 0.f;
            }
        }
#pragma unroll
        for (int rr = 0; rr < 4; ++rr) {
            float v = sp[rr];
            v += __shfl_xor(v, 1, 64);
            v += __shfl_xor(v, 2, 64);
            v += __shfl_xor(v, 4, 64);
            v += __shfl_xor(v, 8, 64);
            const int i = mi * 16 + lk * 4 + rr;
            if (l15 == 0 && i < n_c) {
                const int gi = glist[i];
                row_loss[gi] = (n_c > 1) ? v / (float)(n_c - 1) : 0.f;
                validf[gi] = (n_c > 1) ? 1.f : 0.f;
            }
        }
    }
}

// ---------------- kernel 4: final scalar reduce ---------------------------
__global__ __launch_bounds__(256) void k_final(const float* __restrict__ row_loss,
                                               const float* __restrict__ validf,
                                               float* __restrict__ out) {
    __shared__ float ls[256];
    __shared__ float vs[256];
    float l = 0.f, v = 0.f;
    for (int r = threadIdx.x; r < BN; r += 256) {
        l += row_loss[r] * validf[r];
        v += validf[r];
    }
    ls[threadIdx.x] = l; vs[threadIdx.x] = v;
    __syncthreads();
    for (int st = 128; st > 0; st >>= 1) {
        if (threadIdx.x < st) {
            ls[threadIdx.x] += ls[threadIdx.x + st];
            vs[threadIdx.x] += vs[threadIdx.x + st];
        }
        __syncthreads();
    }
    if (threadIdx.x == 0) out[0] = (vs[0] > 0.f) ? ls[0] / fmaxf(vs[0], 1.f) : 0.f;
}

extern "C" void kernel_launch(void* const* d_in, const int* in_sizes, int n_in,
                              void* d_out, int out_size, void* d_ws, size_t ws_size,
                              hipStream_t stream) {
    const float* z      = (const float*)d_in[0];
    const int*   labels = (const int*)d_in[1];
    float* out = (float*)d_out;

    char* ws = (char*)d_ws;
    // zbf 4MB | sn_part 4x8192 f32 | row_loss | validf | cls_cnt | cls_idx
    unsigned short* zbf = (unsigned short*)ws;
    size_t off = (size_t)BN * DD * sizeof(unsigned short);
    float* sn_part = (float*)(ws + off);  off += 4 * BN * sizeof(float);
    float* rl      = (float*)(ws + off);  off += BN * sizeof(float);
    float* vf      = (float*)(ws + off);  off += BN * sizeof(float);
    int*   cls_cnt = (int*)(ws + off);    off += 1024;
    int*   cls_idx = (int*)(ws + off);    off += 100 * CAPI * sizeof(int);

    k_prep  <<<1024, 256, 0, stream>>>(z, zbf, cls_cnt);
    k_bucket<<<32, 256, 0, stream>>>(labels, cls_cnt, cls_idx);
    k_passA <<<256, 512, 0, stream>>>(zbf, sn_part);
    k_passB <<<100, 256, 0, stream>>>(zbf, sn_part, cls_cnt, cls_idx, rl, vf);
    k_final <<<1, 256, 0, stream>>>(rl, vf, out);
}

// Round 5
// 95.610 us; speedup vs baseline: 3.8071x; 1.0309x over previous
//
#include <hip/hip_runtime.h>
#include <hip/hip_bf16.h>

// Supervised contrastive loss, B=8192, D=256, T=0.07, 100 classes.
//   prep:   z f32 -> bf16 (ws); zero sn + cls_cnt
//   bucket: per-class index lists
//   passA:  SYMMETRIC row sums of exp(z@z^T/T): upper block-triangle only.
//           Strip pairs (r, 63-r) -> 130 col-steps each (balanced). Off-diag
//           steps add row-sums to sn[rows] and col-sums to sn[cols] (symmetry);
//           diagonal steps add row-sums only, i==j masked. 256-thr blocks,
//           64-col dbuf LDS staging (64KB -> 2 blocks/CU), fire-and-forget
//           f32 atomics.
//   passB:  per class: gather to LDS, all-pairs MFMA (bitwise-equal d to
//           passA) -> sum_same -> sum_neg = sn - sum_same; pair-loss pass
//           split over grid.y. row_loss/validf written for every row.
//   final:  mean over valid rows -> d_out[0]

#define BN 8192
#define DD 256
#define INV_T (1.0f / 0.07f)
#define CAPI 256
#define CAP 160

typedef __attribute__((ext_vector_type(8))) __bf16 bf16x8;
typedef __attribute__((ext_vector_type(4))) float f32x4;

typedef const __attribute__((address_space(1))) void gas_void;
typedef __attribute__((address_space(3))) void las_void;

static __device__ __forceinline__ void gld_lds16(const void* g, void* l) {
    __builtin_amdgcn_global_load_lds((gas_void*)g, (las_void*)l, 16, 0, 0);
}

static __device__ __forceinline__ unsigned short f2bf(float f) {
    unsigned int u = __builtin_bit_cast(unsigned int, f);
    u = (u + 0x7FFFu + ((u >> 16) & 1u)) >> 16;   // RNE, inputs finite
    return (unsigned short)u;
}

// ---------------- kernel 1: convert z to bf16, zero sn/cls_cnt ------------
__global__ __launch_bounds__(256) void k_prep(const float* __restrict__ z,
                                              unsigned short* __restrict__ zbf,
                                              float* __restrict__ sn,
                                              int* __restrict__ cls_cnt) {
    const int gid = blockIdx.x * 256 + threadIdx.x;       // 262144 threads
    const float4* z4 = (const float4*)z;
    float4 v0 = z4[gid * 2 + 0];
    float4 v1 = z4[gid * 2 + 1];
    unsigned short r[8];
    r[0] = f2bf(v0.x); r[1] = f2bf(v0.y); r[2] = f2bf(v0.z); r[3] = f2bf(v0.w);
    r[4] = f2bf(v1.x); r[5] = f2bf(v1.y); r[6] = f2bf(v1.z); r[7] = f2bf(v1.w);
    ((uint4*)zbf)[gid] = *(const uint4*)r;
    if (gid < BN) sn[gid] = 0.f;
    if (blockIdx.x == 0 && threadIdx.x < 100) cls_cnt[threadIdx.x] = 0;
}

// ---------------- kernel 1b: bucket rows by class -------------------------
__global__ __launch_bounds__(256) void k_bucket(const int* __restrict__ labels,
                                                int* __restrict__ cls_cnt,
                                                int* __restrict__ cls_idx) {
    const int gid = blockIdx.x * 256 + threadIdx.x;
    if (gid < BN) {
        const int c = labels[gid];
        const int slot = atomicAdd(&cls_cnt[c], 1);
        if (slot < CAPI) cls_idx[c * CAPI + slot] = gid;
    }
}

// ---------------- kernel 2: symmetric row/col sums of exp ------------------
// Grid 512 = 32 strip-pairs x 16 splits. 256 thr = 4 waves x 32 rows.
__global__ __launch_bounds__(256) void k_passA(const unsigned short* __restrict__ zbf,
                                               float* __restrict__ sn) {
    __shared__ char Bb[2][32768];             // [64 cols][512 B], swizzled
    __shared__ float cs_lds[64];

    const int tid = threadIdx.x;
    const int w = tid >> 6, lane = tid & 63;
    const int l15 = lane & 15, lk = lane >> 4;
    const int p = blockIdx.x >> 4, q = blockIdx.x & 15;
    const int r0 = p, r1 = 63 - p;
    const int n0 = 128 - 2 * r0;              // jobs for strip r0; total 130
    const int jlo = (130 * q) >> 4, jhi = (130 * (q + 1)) >> 4;
    const char* zb = (const char*)zbf;

    auto cstepOf = [&](int j, int& s, int& c) {
        if (j < n0) { s = r0; c = 2 * r0 + j; }
        else        { s = r1; c = 2 * r1 + (j - n0); }
    };
    auto stage = [&](int buf, int c) {
        const char* gB = zb + (size_t)c * 64 * 512;
        char* lb = Bb[buf];
#pragma unroll
        for (int qq = 0; qq < 8; ++qq) {
            const int s = (qq * 256 + tid) * 16;
            const int col = s >> 9, koff = s & 511;
            const int ksrc = koff ^ ((col & 7) << 4);   // pre-swizzled source
            gld_lds16(gB + (size_t)col * 512 + ksrc, lb + s);
        }
    };

    bf16x8 a[2][8];
    float snp[2][4];
    int igr[2][4];

    auto flush = [&]() {
#pragma unroll
        for (int m = 0; m < 2; ++m)
#pragma unroll
            for (int rr = 0; rr < 4; ++rr) {
                float v = snp[m][rr];
                v += __shfl_xor(v, 1, 64);
                v += __shfl_xor(v, 2, 64);
                v += __shfl_xor(v, 4, 64);
                v += __shfl_xor(v, 8, 64);
                if (l15 == 0) atomicAdd(&sn[igr[m][rr]], v);
            }
    };

    int s0, c0_; cstepOf(jlo, s0, c0_);
    stage(0, c0_);
    if (tid < 64) cs_lds[tid] = 0.f;

    int cur = -1, buf = 0;
    __syncthreads();                                    // stage(0) drained

    for (int jj = jlo; jj < jhi; ++jj) {
        int s, c; cstepOf(jj, s, c);
        const bool diag = ((c >> 1) == s);
        if (s != cur) {
            if (cur >= 0) flush();
#pragma unroll
            for (int m = 0; m < 2; ++m) {
                const char* ap = zb + (size_t)(s * 128 + w * 32 + m * 16 + l15) * 512 + lk * 16;
#pragma unroll
                for (int kf = 0; kf < 8; ++kf) a[m][kf] = *(const bf16x8*)(ap + kf * 64);
#pragma unroll
                for (int rr = 0; rr < 4; ++rr) {
                    snp[m][rr] = 0.f;
                    igr[m][rr] = s * 128 + w * 32 + m * 16 + lk * 4 + rr;
                }
            }
            cur = s;
        }
        if (jj + 1 < jhi) { int s2, c2; cstepOf(jj + 1, s2, c2); stage(buf ^ 1, c2); }

        const char* bp0 = Bb[buf];
#pragma unroll
        for (int n = 0; n < 4; ++n) {
            const int col = n * 16 + l15;
            const char* bp = bp0 + col * 512;
            const int sw = (col & 7) << 4;
            bf16x8 b[8];
#pragma unroll
            for (int kf = 0; kf < 8; ++kf)
                b[kf] = *(const bf16x8*)(bp + ((lk * 16 + kf * 64) ^ sw));
            const int jg = c * 64 + col;
            float cs_n = 0.f;
#pragma unroll
            for (int m = 0; m < 2; ++m) {
                f32x4 acc = {};
#pragma unroll
                for (int kf = 0; kf < 8; ++kf)
                    acc = __builtin_amdgcn_mfma_f32_16x16x32_bf16(a[m][kf], b[kf], acc, 0, 0, 0);
#pragma unroll
                for (int rr = 0; rr < 4; ++rr) {
                    float e = __expf(acc[rr] * INV_T);
                    if (diag && igr[m][rr] == jg) e = 0.f;   // mask self
                    snp[m][rr] += e;
                    cs_n += e;
                }
            }
            // col-sum: reduce over lk groups (rows), lanes<16 hold col totals
            cs_n += __shfl_xor(cs_n, 16, 64);
            cs_n += __shfl_xor(cs_n, 32, 64);
            if (lane < 16) atomicAdd(&cs_lds[col], cs_n);
        }
        __syncthreads();
        if (tid < 64) {
            const float v = cs_lds[tid];
            if (!diag) atomicAdd(&sn[c * 64 + tid], v);     // symmetric contrib
            cs_lds[tid] = 0.f;
        }
        __syncthreads();
        buf ^= 1;
    }
    flush();
}

// ---------------- kernel 3: per-class positive pairs ----------------------
// Grid (100, 4) x 256 thr. sum_same recomputed per block; pair-loss split on y.
__global__ __launch_bounds__(256) void k_passB(const unsigned short* __restrict__ zbf,
                                               const float* __restrict__ sn,
                                               const int* __restrict__ cls_cnt,
                                               const int* __restrict__ cls_idx,
                                               float* __restrict__ row_loss,
                                               float* __restrict__ validf) {
    __shared__ char Zc[CAP * 512];            // swizzled [row][512 B]
    __shared__ int glist[CAP];
    __shared__ float snl[CAP];
    __shared__ float sums[CAP];

    const int c = blockIdx.x;
    const int sy = blockIdx.y;
    const int tid = threadIdx.x;
    const int w = tid >> 6, lane = tid & 63;
    const int l15 = lane & 15, lk = lane >> 4;
    const char* zb = (const char*)zbf;

    const int n_c = min(cls_cnt[c], CAP);
    const int nt = (n_c + 15) >> 4;
    const int rows_p = nt * 16;

    if (tid < n_c) glist[tid] = cls_idx[c * CAPI + tid];
    __syncthreads();

    for (int e = w; e < rows_p; e += 4) {
        uint2 v = {0u, 0u};
        if (e < n_c) v = *(const uint2*)(zb + (size_t)glist[e] * 512 + lane * 8);
        *(uint2*)(Zc + e * 512 + ((lane * 8) ^ ((e & 7) << 4))) = v;
    }
    __syncthreads();

    // ---- pass 1: sum_same (all waves, all tiles) ----
    for (int mi = w; mi < nt; mi += 4) {
        const int rowA = mi * 16 + l15;
        bf16x8 a[8];
        const char* ap = Zc + rowA * 512;
        const int swa = (rowA & 7) << 4;
#pragma unroll
        for (int kf = 0; kf < 8; ++kf)
            a[kf] = *(const bf16x8*)(ap + ((lk * 16 + kf * 64) ^ swa));
        float sp[4] = {};
        for (int nj = 0; nj < nt; ++nj) {
            const int colB = nj * 16 + l15;
            bf16x8 b[8];
            const char* bp = Zc + colB * 512;
            const int swb = (colB & 7) << 4;
#pragma unroll
            for (int kf = 0; kf < 8; ++kf)
                b[kf] = *(const bf16x8*)(bp + ((lk * 16 + kf * 64) ^ swb));
            f32x4 acc = {};
#pragma unroll
            for (int kf = 0; kf < 8; ++kf)
                acc = __builtin_amdgcn_mfma_f32_16x16x32_bf16(a[kf], b[kf], acc, 0, 0, 0);
#pragma unroll
            for (int rr = 0; rr < 4; ++rr) {
                const int i = mi * 16 + lk * 4 + rr;
                const float e = __expf(acc[rr] * INV_T);
                sp[rr] += (colB < n_c && i != colB) ? e : 0.f;
            }
        }
#pragma unroll
        for (int rr = 0; rr < 4; ++rr) {
            float v = sp[rr];
            v += __shfl_xor(v, 1, 64);
            v += __shfl_xor(v, 2, 64);
            v += __shfl_xor(v, 4, 64);
            v += __shfl_xor(v, 8, 64);
            if (l15 == 0) sums[mi * 16 + lk * 4 + rr] = v;
        }
    }
    __syncthreads();
    if (tid < n_c) snl[tid] = sn[glist[tid]] - sums[tid];   // sum_neg
    __syncthreads();

    // ---- pass 2: pair losses (this block handles mi % 4 == sy) ----
    const int mi = sy + 4 * w;
    if (mi < nt) {
        const int rowA = mi * 16 + l15;
        bf16x8 a[8];
        const char* ap = Zc + rowA * 512;
        const int swa = (rowA & 7) << 4;
#pragma unroll
        for (int kf = 0; kf < 8; ++kf)
            a[kf] = *(const bf16x8*)(ap + ((lk * 16 + kf * 64) ^ swa));
        float sneg[4];
#pragma unroll
        for (int rr = 0; rr < 4; ++rr) {
            const int i = mi * 16 + lk * 4 + rr;
            sneg[rr] = (i < n_c) ? snl[i] : 0.f;
        }
        float sp[4] = {};
        for (int nj = 0; nj < nt; ++nj) {
            const int colB = nj * 16 + l15;
            bf16x8 b[8];
            const char* bp = Zc + colB * 512;
            const int swb = (colB & 7) << 4;
#pragma unroll
            for (int kf = 0; kf < 8; ++kf)
                b[kf] = *(const bf16x8*)(bp + ((lk * 16 + kf * 64) ^ swb));
            f32x4 acc = {};
#pragma unroll
            for (int kf = 0; kf < 8; ++kf)
                acc = __builtin_amdgcn_mfma_f32_16x16x32_bf16(a[kf], b[kf], acc, 0, 0, 0);
#pragma unroll
            for (int rr = 0; rr < 4; ++rr) {
                const int i = mi * 16 + lk * 4 + rr;
                const float t = log1pf(sneg[rr] * __expf(-acc[rr] * INV_T));
                sp[rr] += (colB < n_c && i != colB) ? t : 0.f;
            }
        }
#pragma unroll
        for (int rr = 0; rr < 4; ++rr) {
            float v = sp[rr];
            v += __shfl_xor(v, 1, 64);
            v += __shfl_xor(v, 2, 64);
            v += __shfl_xor(v, 4, 64);
            v += __shfl_xor(v, 8, 64);
            const int i = mi * 16 + lk * 4 + rr;
            if (l15 == 0 && i < n_c) {
                const int gi = glist[i];
                row_loss[gi] = (n_c > 1) ? v / (float)(n_c - 1) : 0.f;
                validf[gi] = (n_c > 1) ? 1.f : 0.f;
            }
        }
    }
}

// ---------------- kernel 4: final scalar reduce ---------------------------
__global__ __launch_bounds__(1024) void k_final(const float* __restrict__ row_loss,
                                                const float* __restrict__ validf,
                                                float* __restrict__ out) {
    __shared__ float ls[16], vs[16];
    float l = 0.f, v = 0.f;
    for (int r = threadIdx.x; r < BN; r += 1024) {
        const float f = validf[r];
        l += row_loss[r] * f;
        v += f;
    }
#pragma unroll
    for (int m = 1; m < 64; m <<= 1) {
        l += __shfl_xor(l, m, 64);
        v += __shfl_xor(v, m, 64);
    }
    if ((threadIdx.x & 63) == 0) { ls[threadIdx.x >> 6] = l; vs[threadIdx.x >> 6] = v; }
    __syncthreads();
    if (threadIdx.x == 0) {
        float L = 0.f, V = 0.f;
        for (int i = 0; i < 16; ++i) { L += ls[i]; V += vs[i]; }
        out[0] = (V > 0.f) ? L / fmaxf(V, 1.f) : 0.f;
    }
}

extern "C" void kernel_launch(void* const* d_in, const int* in_sizes, int n_in,
                              void* d_out, int out_size, void* d_ws, size_t ws_size,
                              hipStream_t stream) {
    const float* z      = (const float*)d_in[0];
    const int*   labels = (const int*)d_in[1];
    float* out = (float*)d_out;

    char* ws = (char*)d_ws;
    // zbf 4MB | sn | row_loss | validf | cls_cnt | cls_idx
    unsigned short* zbf = (unsigned short*)ws;
    size_t off = (size_t)BN * DD * sizeof(unsigned short);
    float* sn      = (float*)(ws + off);  off += BN * sizeof(float);
    float* rl      = (float*)(ws + off);  off += BN * sizeof(float);
    float* vf      = (float*)(ws + off);  off += BN * sizeof(float);
    int*   cls_cnt = (int*)(ws + off);    off += 1024;
    int*   cls_idx = (int*)(ws + off);    off += 100 * CAPI * sizeof(int);

    k_prep  <<<1024, 256, 0, stream>>>(z, zbf, sn, cls_cnt);
    k_bucket<<<32, 256, 0, stream>>>(labels, cls_cnt, cls_idx);
    k_passA <<<512, 256, 0, stream>>>(zbf, sn);
    k_passB <<<dim3(100, 4), 256, 0, stream>>>(zbf, sn, cls_cnt, cls_idx, rl, vf);
    k_final <<<1, 1024, 0, stream>>>(rl, vf, out);
}